// Round 9
// baseline (163.685 us; speedup 1.0000x reference)
//
#include <hip/hip_runtime.h>

// Post_Prob_GS: B=8, N=256 points, grid 128x128 (HW=16384), stride 4.
// out[b, n, hw] = softmax over n of likelihood; n==256 is the background term.
//
// Round 9: phase-separated design.
//  - prep_kernel: per-point coeffs (expanded quadratic, log2e-scaled).
//  - reduce_kernel: m2 = mf + log2(sum) per (b,hw) -> ws; writes bk row.
//    4 n-groups x 64 pts, 2-eval recompute, low VGPR, 32 waves/CU.
//  - row_store_kernel: ONE WAVE PER QUARTER-ROW. Coeffs = 2 uniform loads
//    per wave total; inner loop = m2 float4 load + 11 FMA + 4 v_exp_f32 +
//    one 1KB-contiguous wave store. 16KB sequential per wave == the fill
//    kernel's write stream. No LDS, no barriers, 8 waves/SIMD.

#define HWC 16384
#define NPTS 256
#define NBATCH 8

#define K_LOG2E 1.4426950408889634f
// log2e*(-0.5*100^2) + log2(0.15)
#define BK_CONST (-7216.2121700389835f)

#if __has_builtin(__builtin_amdgcn_exp2f)
#define EXP2(x) __builtin_amdgcn_exp2f(x)
#else
#define EXP2(x) exp2f(x)
#endif

__global__ __launch_bounds__(256) void prep_kernel(
    const float* __restrict__ scale,     // (B,N,2)
    const float* __restrict__ rotation,  // (B,N,1)
    const float* __restrict__ points,    // (B,N,2)
    float4* __restrict__ P)              // (B*N) x 2 float4
{
    const int i = blockIdx.x * 256 + threadIdx.x;   // 0..2047 = b*256+n
    if (i >= NBATCH * NPTS) return;

    float sx = fminf(fmaxf(32.0f * scale[i * 2 + 0], 2.0f), 100.0f);
    float sy = fminf(fmaxf(32.0f * scale[i * 2 + 1], 2.0f), 100.0f);
    float sx2 = sx * sx, sy2 = sy * sy;

    float th = rotation[i];
    float s, c;
    sincosf(th, &s, &c);
    float cov_a = c * c * sx2 + s * s * sy2;
    float cov_b = c * s * (sx2 - sy2);
    float cov_d = s * s * sx2 + c * c * sy2;
    float det  = sx2 * sy2;
    float rdet = 1.0f / det;

    float KA = -0.5f * K_LOG2E * (cov_d * rdet);
    float KB =         K_LOG2E * (cov_b * rdet);
    float KD = -0.5f * K_LOG2E * (cov_a * rdet);

    float px = points[i * 2 + 0];
    float py = points[i * 2 + 1];

    // zK = KA*gx^2 + KB*gx*gy + KD*gy^2 + cx*gx + cy*gy + cz
    float cx = -(2.0f * KA * px + KB * py);
    float cy = -(KB * px + 2.0f * KD * py);
    float cz = KA * px * px + KB * px * py + KD * py * py;

    float l2det = log2f(det);
    float HLK = -0.5f * l2det;

    P[i * 2 + 0] = make_float4(KA, KB, KD, cx);
    P[i * 2 + 1] = make_float4(cy, cz + HLK, HLK, l2det);
}

#define LIKE(q0, q1) fmaf((q0).x, gxx, fmaf((q0).y, gxy, fmaf((q0).z, gyy, \
                     fmaf((q0).w, gx,  fmaf((q1).x, gy, (q1).y)))))

// m2[b,hw] = softmax log2-normalizer; also writes the background output row.
__global__ __launch_bounds__(256) void reduce_kernel(
    const float4* __restrict__ P,    // packed coeffs in ws
    float* __restrict__ m2arr,       // (B, HW) in ws
    float* __restrict__ out)         // (B, 257, HW) -- bk row only
{
    __shared__ float sM[256];
    __shared__ float sBZ[256];
    __shared__ float sBLD[256];
    __shared__ float sS[256];

    const int b      = blockIdx.x >> 8;          // 256 blocks per batch
    const int hwbase = (blockIdx.x & 255) << 6;  // 64 hw per block
    const int tid    = threadIdx.x;
    const int lane   = tid & 63;
    const int hw     = hwbase + lane;
    const int g      = __builtin_amdgcn_readfirstlane(tid >> 6);  // 4 groups x 64 pts

    const float gx = (float)((hw & 127) * 4 + 2);
    const float gy = (float)((hw >> 7) * 4 + 2);
    const float gxx = gx * gx, gxy = gx * gy, gyy = gy * gy;

    const float4* __restrict__ Pb = P + (b * NPTS + g * 64) * 2;

    // ---- pass A: per-thread max + first-argmax over 64 points ----
    float m = -INFINITY, bz = -INFINITY, bld = 0.0f;
    #pragma unroll 8
    for (int i = 0; i < 64; ++i) {
        float4 q0 = Pb[i * 2 + 0];
        float4 q1 = Pb[i * 2 + 1];
        float like = LIKE(q0, q1);
        m = fmaxf(m, like);
        float z = like - q1.z;
        bool gt = z > bz;               // strict > : first occurrence wins
        bz  = gt ? z    : bz;
        bld = gt ? q1.w : bld;
    }
    sM[tid] = m; sBZ[tid] = bz; sBLD[tid] = bld;
    __syncthreads();

    // merge groups ascending g (== ascending n: first-max wins)
    float mf = sM[lane], bzf = sBZ[lane], bldf = sBLD[lane];
    #pragma unroll
    for (int q = 1; q < 4; ++q) {
        mf = fmaxf(mf, sM[lane + q * 64]);
        float zq = sBZ[lane + q * 64];
        bool gt = zq > bzf;
        bzf  = gt ? zq : bzf;
        bldf = gt ? sBLD[lane + q * 64] : bldf;
    }
    const float bk = BK_CONST - bzf - bldf;
    mf = fmaxf(mf, bk);

    // ---- pass B: sum of exp2 ----
    float s = 0.0f;
    #pragma unroll 8
    for (int i = 0; i < 64; ++i) {
        float4 q0 = Pb[i * 2 + 0];
        float4 q1 = Pb[i * 2 + 1];
        s += EXP2(LIKE(q0, q1) - mf);
    }
    sS[tid] = s;
    __syncthreads();

    float sum = EXP2(bk - mf);
    #pragma unroll
    for (int q = 0; q < 4; ++q) sum += sS[lane + q * 64];
    const float m2 = mf + log2f(sum);

    if (tid < 64) {
        m2arr[b * HWC + hw] = m2;
        out[((size_t)b * 257 + 256) * HWC + hw] = EXP2(bk - m2);
    }
}

// One wave per quarter-row: 16KB sequential stores, coeffs uniform per wave.
__global__ __launch_bounds__(256) void row_store_kernel(
    const float4* __restrict__ P,    // packed coeffs in ws
    const float* __restrict__ m2arr, // (B, HW) in ws
    float* __restrict__ out)         // (B, 257, HW)
{
    const int r    = blockIdx.x;                 // row 0..2047 = b*256+n
    const int b    = r >> 8;
    const int lane = threadIdx.x & 63;
    const int wid  = __builtin_amdgcn_readfirstlane(threadIdx.x >> 6); // quarter

    // coeffs: wave-uniform, loaded ONCE
    const float4 q0 = P[r * 2 + 0];
    const float4 q1 = P[r * 2 + 1];

    // lane geometry: cell = wid*4096 + s*256 + lane*4
    const float gx0 = (float)(((lane & 31) * 4) * 4 + 2);   // x*4+2
    const float gx1 = gx0 + 4.0f, gx2 = gx0 + 8.0f, gx3 = gx0 + 12.0f;
    float gy = (float)((wid * 32 + (lane >> 5)) * 4 + 2);   // advances by 8/step

    const float* __restrict__ m2b = m2arr + b * HWC + wid * 4096 + lane * 4;
    float* __restrict__ dst = out + (size_t)(r + b) * HWC + wid * 4096 + lane * 4;

    #pragma unroll 4
    for (int s = 0; s < 16; ++s) {
        const float4 mm = *reinterpret_cast<const float4*>(m2b + s * 256);
        const float gcoef = fmaf(q0.y, gy, q0.w);                   // KB*gy+cx
        const float base  = fmaf(fmaf(q0.z, gy, q1.x), gy, q1.y);   // KD*gy^2+cy*gy+cz+HLK
        float4 e;
        e.x = EXP2(fmaf(fmaf(q0.x, gx0, gcoef), gx0, base) - mm.x);
        e.y = EXP2(fmaf(fmaf(q0.x, gx1, gcoef), gx1, base) - mm.y);
        e.z = EXP2(fmaf(fmaf(q0.x, gx2, gcoef), gx2, base) - mm.z);
        e.w = EXP2(fmaf(fmaf(q0.x, gx3, gcoef), gx3, base) - mm.w);
        *reinterpret_cast<float4*>(dst + s * 256) = e;
        gy += 8.0f;
    }
}

extern "C" void kernel_launch(void* const* d_in, const int* in_sizes, int n_in,
                              void* d_out, int out_size, void* d_ws, size_t ws_size,
                              hipStream_t stream) {
    const float* scale    = (const float*)d_in[0];
    const float* rotation = (const float*)d_in[1];
    const float* points   = (const float*)d_in[2];
    float* out = (float*)d_out;
    float4* P  = (float4*)d_ws;                               // 64 KB
    float* m2  = (float*)((char*)d_ws + 65536);               // 512 KB
    (void)in_sizes; (void)n_in; (void)out_size; (void)ws_size;

    prep_kernel<<<dim3(NBATCH), dim3(256), 0, stream>>>(scale, rotation, points, P);
    reduce_kernel<<<dim3(NBATCH * (HWC / 64)), dim3(256), 0, stream>>>(P, m2, out);
    row_store_kernel<<<dim3(NBATCH * NPTS), dim3(256), 0, stream>>>(P, m2, out);
}